// Round 11
// baseline (296.037 us; speedup 1.0000x reference)
//
#include <hip/hip_runtime.h>

// ---------------- problem constants ----------------
constexpr int LDIM = 4;
constexpr int MDIM = 64;
constexpr int FDIM = 128;
constexpr int EDIM = 128;
constexpr int RAWD = 641;
constexpr int HDIM = 320;
constexpr int LM   = LDIM * MDIM;   // 256
constexpr int KXY  = LM + FDIM;     // 384
constexpr int NXY  = 2 * HDIM;      // 640

typedef _Float16 f16x8 __attribute__((ext_vector_type(8)));
typedef _Float16 f16x4 __attribute__((ext_vector_type(4)));
typedef float    f32x4 __attribute__((ext_vector_type(4)));

constexpr float WSCALE  = 256.f;       // weights pre-scaled so lo-plane is f16-normal
constexpr float WSINV   = 1.f / 256.f; // exact pow2, applied in epilogue

// ---------------- small event/node kernels ----------------
__global__ void k_init(int* t_node_bits, int* counts, int* cursor2, int* cursor, int Nn)
{
    int n = blockIdx.x * blockDim.x + threadIdx.x;
    if (n < Nn) {
        t_node_bits[n] = 0xBF800000;  // -1.0f; timestamps >= 0
        counts[n]  = 0;
        cursor2[n] = 0;
    }
    if (n == 0) cursor[0] = 0;
}

__global__ void k_ev1(const int* __restrict__ src, const float* __restrict__ ts,
                      int* t_node_bits, int* counts, int Bev)
{
    int b = blockIdx.x * blockDim.x + threadIdx.x;
    if (b >= Bev) return;
    int s = src[b];
    atomicMax(&t_node_bits[s], __float_as_int(ts[b]));
    atomicAdd(&counts[s], 1);
}

__global__ void k_node(const int* __restrict__ t_node_bits, const int* __restrict__ counts,
                       const float* __restrict__ last_update, const float* __restrict__ lambs,
                       float* t_safe, float* decay, int* start, int* cursor, int Nn)
{
    int n = blockIdx.x * blockDim.x + threadIdx.x;
    if (n >= Nn) return;
    int c = counts[n];
    float lu = last_update[n];
    float tsn = (c > 0) ? __int_as_float(t_node_bits[n]) : lu;
    t_safe[n] = tsn;
    float d = tsn - lu;
    #pragma unroll
    for (int li = 0; li < LDIM; ++li)
        decay[n * LDIM + li] = expf(-d * lambs[li]);
    start[n] = atomicAdd(cursor, c);
}

__global__ void k_ev2(const int* __restrict__ src, const int* __restrict__ tgt,
                      const float* __restrict__ ts, const float* __restrict__ t_safe,
                      const int* __restrict__ start, int* cursor2,
                      const float* __restrict__ lambs,
                      int* sorted_tgt, float4* sorted_w, int Bev)
{
    int b = blockIdx.x * blockDim.x + threadIdx.x;
    if (b >= Bev) return;
    int s = src[b];
    int pos = start[s] + atomicAdd(&cursor2[s], 1);
    sorted_tgt[pos] = tgt[b];
    float dt = t_safe[s] - ts[b];
    sorted_w[pos] = make_float4(expf(-dt * lambs[0]), expf(-dt * lambs[1]),
                                expf(-dt * lambs[2]), expf(-dt * lambs[3]));
}

// ---------------- prep: weights [N][K] scaled f16 hi/lo + A1 f16 pack ----------------
__global__ void k_prep(const float* __restrict__ W1, const float* __restrict__ W2,
                       const float* __restrict__ We, const float* __restrict__ Ws,
                       const float* __restrict__ mem, const float* __restrict__ nf,
                       _Float16* WpH, _Float16* WpL, _Float16* W2H, _Float16* W2L,
                       _Float16* WeH, _Float16* WeL, _Float16* WsH, _Float16* WsL,
                       _Float16* A1, int packtot)
{
    int idx = blockIdx.x * blockDim.x + threadIdx.x;
    constexpr int T1 = NXY * KXY;    // 245760  Wpack [640][384]
    constexpr int T2 = MDIM * HDIM;  // 20480   W2 [64][320]
    constexpr int T3 = MDIM * LM;    // 16384   We [64][256]
    constexpr int T4 = EDIM * MDIM;  // 8192    Ws [128][64]
    constexpr int TW = T1 + T2 + T3 + T4;
    if (idx < TW) {
        float v; _Float16 *H, *L; int o;
        if (idx < T1) {
            int n = idx / KXY, k = idx % KXY;
            if (n < HDIM) {
                v = (k < LM) ? W1[(long)n * RAWD + k] : 0.f;            // X cols: src-mem
            } else {
                int hh = n - HDIM;
                v = (k < LM) ? W1[(long)hh * RAWD + LM + k]              // Y cols: tgt-mem
                             : W1[(long)hh * RAWD + 2 * LM + (k - LM)];  //         tgt-feat
            }
            H = WpH; L = WpL; o = idx;
        } else if (idx < T1 + T2) {
            o = idx - T1; v = W2[o]; H = W2H; L = W2L;
        } else if (idx < T1 + T2 + T3) {
            o = idx - T1 - T2; v = We[o]; H = WeH; L = WeL;
        } else {
            o = idx - T1 - T2 - T3; v = Ws[o]; H = WsH; L = WsL;
        }
        float xs = WSCALE * v;
        _Float16 hh = (_Float16)xs;
        _Float16 ll = (_Float16)(xs - (float)hh);
        H[o] = hh; L[o] = ll;
    } else {
        int r = idx - TW;
        if (r < packtot) {
            int n = r / KXY, k = r % KXY;
            float v = (k < LM) ? mem[(long)n * LM + k] : nf[(long)n * FDIM + (k - LM)];
            A1[r] = (_Float16)v;
        }
    }
}

// ---------------- fused gather + msg-GEMM + memory update ----------------
// Block = 4 waves, 4 nodes (one per wave). Phase 1: per-wave gather of
// h[4][320] into LDS rows [wv*4+li]. Phase 2: block tile M=16 (4 nodes x 4 li),
// each wave computes one 16-col tile of msg = h @ W2^T (K=320, hi+lo planes),
// epilogue writes updated = mem*decay + where(has, msg, 0) as f16.
__global__ __launch_bounds__(256) void k_gmsg(
    const _Float16* __restrict__ C1, const float4* __restrict__ sorted_w,
    const int* __restrict__ sorted_tgt, const int* __restrict__ startb,
    const int* __restrict__ counts,
    const float* __restrict__ W1, const float* __restrict__ b1,
    const _Float16* __restrict__ W2H, const _Float16* __restrict__ W2L,
    const float* __restrict__ b2, const _Float16* __restrict__ A1,
    const float* __restrict__ decay, _Float16* __restrict__ updh, int Nn)
{
    constexpr int HP = HDIM + 8;                 // 328: row stride, 16B-aligned, 2-way banks
    __shared__ _Float16 hs[16][HP];
    const int lane = threadIdx.x & 63;
    const int wv   = threadIdx.x >> 6;
    const int n    = blockIdx.x * 4 + wv;

    // ---- phase 1: gather (identical math to round-10 k_gather) ----
    float4 b4 = *(const float4*)&b1[lane * 4];
    float bbA[4] = {b4.x, b4.y, b4.z, b4.w};
    float bbB = b1[256 + lane];
    float wlA[4], wlB;
    #pragma unroll
    for (int j = 0; j < 4; ++j)
        wlA[j] = W1[(long)(lane * 4 + j) * RAWD + (RAWD - 1)];
    wlB = W1[(long)(256 + lane) * RAWD + (RAWD - 1)];

    int cnt = (n < Nn) ? counts[n] : 0;
    if (cnt == 0) {
        #pragma unroll
        for (int li = 0; li < 4; ++li) {
            *(f16x4*)&hs[wv * 4 + li][lane * 4] = (f16x4){0, 0, 0, 0};
            hs[wv * 4 + li][256 + lane] = (_Float16)0.f;
        }
    } else {
        int st = startb[n];
        float zA[4][4], zB[4], sw[4];
        #pragma unroll
        for (int li = 0; li < 4; ++li) { zB[li] = 0.f; sw[li] = 0.f; }
        #pragma unroll
        for (int j = 0; j < 4; ++j)
            #pragma unroll
            for (int li = 0; li < 4; ++li) zA[j][li] = 0.f;

        for (int e = 0; e < cnt; ++e) {
            float4 w = sorted_w[st + e];
            int    t = sorted_tgt[st + e];
            const _Float16* yr = C1 + (long)t * NXY + HDIM;
            f16x4 yA = *(const f16x4*)(yr + lane * 4);
            float  yB = (float)yr[256 + lane];
            float wf[4] = {w.x, w.y, w.z, w.w};
            sw[0] += w.x; sw[1] += w.y; sw[2] += w.z; sw[3] += w.w;
            #pragma unroll
            for (int j = 0; j < 4; ++j) {
                float yv = (float)yA[j];
                #pragma unroll
                for (int li = 0; li < 4; ++li) zA[j][li] += wf[li] * yv;
            }
            #pragma unroll
            for (int li = 0; li < 4; ++li) zB[li] += wf[li] * yB;
        }

        const _Float16* xr = C1 + (long)n * NXY;
        f16x4 xA4 = *(const f16x4*)(xr + lane * 4);
        float xB = (float)xr[256 + lane] + wlB;
        float xA[4];
        #pragma unroll
        for (int j = 0; j < 4; ++j) xA[j] = (float)xA4[j] + wlA[j];
        #pragma unroll
        for (int li = 0; li < 4; ++li) {
            f16x4 hv;
            #pragma unroll
            for (int j = 0; j < 4; ++j)
                hv[j] = (_Float16)fmaxf(xA[j] * sw[li] + zA[j][li] + bbA[j], 0.f);
            *(f16x4*)&hs[wv * 4 + li][lane * 4] = hv;
            hs[wv * 4 + li][256 + lane] = (_Float16)fmaxf(xB * sw[li] + zB[li] + bbB, 0.f);
        }
    }
    __syncthreads();

    // ---- phase 2: msg = h @ W2^T, one 16-col tile per wave ----
    const int lrow = lane & 15, lq = lane >> 4;
    f32x4 acc = (f32x4){0.f, 0.f, 0.f, 0.f};
    for (int k0 = 0; k0 < HDIM; k0 += 32) {
        f16x8 a = *(const f16x8*)&hs[lrow][k0 + lq * 8];
        long bo = (long)(wv * 16 + lrow) * HDIM + k0 + lq * 8;
        f16x8 bh = *(const f16x8*)&W2H[bo];
        f16x8 bl = *(const f16x8*)&W2L[bo];
        acc = __builtin_amdgcn_mfma_f32_16x16x32_f16(a, bh, acc, 0, 0, 0);
        acc = __builtin_amdgcn_mfma_f32_16x16x32_f16(a, bl, acc, 0, 0, 0);
    }

    // ---- epilogue: updated = mem*decay + where(has, msg+b2, 0) ----
    int m = wv * 16 + lrow;                      // output col 0..63
    float bb2 = b2[m];
    #pragma unroll
    for (int r = 0; r < 4; ++r) {
        int r16 = lq * 4 + r;                    // row 0..15 = (node-in-block, li)
        int nib = r16 >> 2, li = r16 & 3;
        int gn = blockIdx.x * 4 + nib;
        if (gn >= Nn) continue;
        float v = acc[r] * WSINV + bb2;
        bool has = counts[gn] > 0;
        float mv = (float)A1[(long)gn * KXY + li * MDIM + m];
        float u = mv * decay[gn * 4 + li] + (has ? v : 0.f);
        updh[((long)gn * 4 + li) * MDIM + m] = (_Float16)u;
    }
}

// ---------------- f16 2-product MFMA GEMM ----------------
// C[M][N] = A[M][K](f16) @ (Bh+Bl)[K][N], B stored [N][K] scaled by 256.
// LDS [rows][32k] f16 (64B rows), 16B-chunk XOR swizzle: phys_chunk = kc ^ ((row>>1)&3).
// 4 waves arranged WM x WN; wave tile (BM/WM) x (BN/WN).
// EPI: 0 -> f16 C; 2 -> leaky f16; 3 -> f32 blend out.
template <int BM, int BN, int WM, int WN, int EPI>
__global__ __launch_bounds__(256) void k_mgemm(
    const _Float16* __restrict__ Ag,
    const _Float16* __restrict__ Bgh, const _Float16* __restrict__ Bgl,
    _Float16* __restrict__ Ch, float* __restrict__ Cf,
    int M, int N, int K,
    const float* __restrict__ bias, const float* __restrict__ x1f,
    const float* __restrict__ theta)
{
    constexpr int BK = 32;
    constexpr int WROWS = BM / WM, WCOLS = BN / WN;
    constexpr int SM = WROWS / 16, SN = WCOLS / 16;
    static_assert(WM * WN == 4 && SM * 16 == WROWS && SN * 16 == WCOLS, "");
    static_assert((BM * 4) % 256 == 0 && (BN * 4) % 256 == 0, "");
    __shared__ _Float16 Ash[BM * BK];
    __shared__ _Float16 Bsh[BN * BK], Bsl[BN * BK];
    const int tid  = threadIdx.x;
    const int w    = tid >> 6, lane = tid & 63;
    const int wm   = w / WN,   wn   = w % WN;
    const int lrow = lane & 15, lq = lane >> 4;
    const long m0 = (long)blockIdx.x * BM;
    const int  n0 = blockIdx.y * BN;

    f32x4 acc[SM][SN];
    #pragma unroll
    for (int s = 0; s < SM; ++s)
        #pragma unroll
        for (int t = 0; t < SN; ++t) acc[s][t] = (f32x4){0.f, 0.f, 0.f, 0.f};

    for (int k0 = 0; k0 < K; k0 += BK) {
        #pragma unroll
        for (int f0 = 0; f0 < BM * 4; f0 += 256) {
            int c = f0 + tid;
            int row = c >> 2, kc = c & 3;
            long gm = m0 + row; if (gm > M - 1) gm = M - 1;
            int soff = row * BK + ((kc ^ ((row >> 1) & 3)) << 3);
            *(int4*)&Ash[soff] = *(const int4*)(Ag + gm * (long)K + k0 + kc * 8);
        }
        #pragma unroll
        for (int f0 = 0; f0 < BN * 4; f0 += 256) {
            int c = f0 + tid;
            int row = c >> 2, kc = c & 3;
            long goff = (long)(n0 + row) * K + k0 + kc * 8;
            int soff = row * BK + ((kc ^ ((row >> 1) & 3)) << 3);
            *(int4*)&Bsh[soff] = *(const int4*)(Bgh + goff);
            *(int4*)&Bsl[soff] = *(const int4*)(Bgl + goff);
        }
        __syncthreads();

        f16x8 a[SM], bh[SN], bl[SN];
        #pragma unroll
        for (int s = 0; s < SM; ++s) {
            int row = wm * WROWS + s * 16 + lrow;
            a[s] = *(const f16x8*)&Ash[row * BK + ((lq ^ ((row >> 1) & 3)) << 3)];
        }
        #pragma unroll
        for (int t = 0; t < SN; ++t) {
            int row = wn * WCOLS + t * 16 + lrow;
            int off = row * BK + ((lq ^ ((row >> 1) & 3)) << 3);
            bh[t] = *(const f16x8*)&Bsh[off];
            bl[t] = *(const f16x8*)&Bsl[off];
        }
        #pragma unroll
        for (int s = 0; s < SM; ++s)
            #pragma unroll
            for (int t = 0; t < SN; ++t) {
                acc[s][t] = __builtin_amdgcn_mfma_f32_16x16x32_f16(a[s], bh[t], acc[s][t], 0, 0, 0);
                acc[s][t] = __builtin_amdgcn_mfma_f32_16x16x32_f16(a[s], bl[t], acc[s][t], 0, 0, 0);
            }
        __syncthreads();
    }

    float th = 0.f;
    if constexpr (EPI == 3) th = theta[0];
    #pragma unroll
    for (int s = 0; s < SM; ++s) {
        #pragma unroll
        for (int t = 0; t < SN; ++t) {
            #pragma unroll
            for (int r = 0; r < 4; ++r) {
                long grow = m0 + wm * WROWS + s * 16 + lq * 4 + r;
                if (grow >= M) continue;
                int col = n0 + wn * WCOLS + t * 16 + lrow;
                float v = acc[s][t][r] * WSINV;
                long idx = grow * (long)N + col;
                if constexpr (EPI == 0) {
                    Ch[idx] = (_Float16)v;
                } else if constexpr (EPI == 2) {
                    float u = v + bias[col];
                    u = u > 0.f ? u : 0.01f * u;
                    Ch[idx] = (_Float16)u;
                } else {
                    float u = v + bias[col];
                    u = u > 0.f ? u : 0.01f * u;
                    Cf[idx] = th * x1f[idx] + (1.f - th) * u;
                }
            }
        }
    }
}

// ---------------- launcher ----------------
extern "C" void kernel_launch(void* const* d_in, const int* in_sizes, int n_in,
                              void* d_out, int out_size, void* d_ws, size_t ws_size,
                              hipStream_t stream)
{
    (void)n_in; (void)out_size; (void)ws_size;
    const float* node_features = (const float*)d_in[0];
    const float* memory        = (const float*)d_in[1];
    const float* last_update   = (const float*)d_in[2];
    const float* lambs         = (const float*)d_in[3];
    const float* theta         = (const float*)d_in[4];
    const float* static_emb    = (const float*)d_in[5];
    const float* W1            = (const float*)d_in[6];
    const float* b1            = (const float*)d_in[7];
    const float* W2            = (const float*)d_in[8];
    const float* b2            = (const float*)d_in[9];
    const float* We            = (const float*)d_in[10];
    const float* be            = (const float*)d_in[11];
    const float* Ws            = (const float*)d_in[12];
    const float* bs            = (const float*)d_in[13];
    const float* timestamps    = (const float*)d_in[14];
    const int*   src           = (const int*)d_in[15];
    const int*   tgt           = (const int*)d_in[16];
    float* out = (float*)d_out;

    const int Nn  = in_sizes[2];   // 20000
    const int Bev = in_sizes[14];  // 100000

    char* base = (char*)d_ws;
    size_t off = 0;
    auto take = [&](size_t bytes) -> void* {
        off = (off + 255) & ~(size_t)255;
        void* r = base + off;
        off += bytes;
        return r;
    };
    int*    t_node_bits = (int*)   take((size_t)Nn * 4);
    int*    counts      = (int*)   take((size_t)Nn * 4);
    int*    startb      = (int*)   take((size_t)Nn * 4);
    int*    cursor2     = (int*)   take((size_t)Nn * 4);
    int*    cursor      = (int*)   take(256);
    float*  t_safe      = (float*) take((size_t)Nn * 4);
    float*  decay       = (float*) take((size_t)Nn * LDIM * 4);
    int*    sorted_tgt  = (int*)   take((size_t)Bev * 4);
    float4* sorted_w    = (float4*)take((size_t)Bev * 16);
    _Float16* WpH = (_Float16*)take((size_t)NXY * KXY * 2);
    _Float16* WpL = (_Float16*)take((size_t)NXY * KXY * 2);
    _Float16* W2H = (_Float16*)take((size_t)MDIM * HDIM * 2);
    _Float16* W2L = (_Float16*)take((size_t)MDIM * HDIM * 2);
    _Float16* WeH = (_Float16*)take((size_t)MDIM * LM * 2);
    _Float16* WeL = (_Float16*)take((size_t)MDIM * LM * 2);
    _Float16* WsH = (_Float16*)take((size_t)EDIM * MDIM * 2);
    _Float16* WsL = (_Float16*)take((size_t)EDIM * MDIM * 2);
    _Float16* A1  = (_Float16*)take((size_t)Nn * KXY * 2);            // 15.4 MB
    _Float16* C1  = (_Float16*)take((size_t)Nn * NXY * 2);            // 25.6 MB
    _Float16* updh= (_Float16*)take((size_t)Nn * LM * 2);             // 10.2 MB
    _Float16* ebuf= (_Float16*)take((size_t)Nn * MDIM * 2);           // 2.6 MB

    const int tb = 256;
    k_init<<<(Nn + tb - 1) / tb, tb, 0, stream>>>(t_node_bits, counts, cursor2, cursor, Nn);
    k_ev1<<<(Bev + tb - 1) / tb, tb, 0, stream>>>(src, timestamps, t_node_bits, counts, Bev);
    k_node<<<(Nn + tb - 1) / tb, tb, 0, stream>>>(t_node_bits, counts, last_update, lambs,
                                                  t_safe, decay, startb, cursor, Nn);
    k_ev2<<<(Bev + tb - 1) / tb, tb, 0, stream>>>(src, tgt, timestamps, t_safe,
                                                  startb, cursor2, lambs,
                                                  sorted_tgt, sorted_w, Bev);
    const int packtot = Nn * KXY;
    const int preptot = NXY * KXY + MDIM * HDIM + MDIM * LM + EDIM * MDIM + packtot;
    k_prep<<<(preptot + tb - 1) / tb, tb, 0, stream>>>(W1, W2, We, Ws,
                                                       memory, node_features,
                                                       WpH, WpL, W2H, W2L,
                                                       WeH, WeL, WsH, WsL,
                                                       A1, packtot);

    const int mb64 = (Nn + 63) / 64;    // 313

    // G1: C1[20000][640](f16) = A1 @ Wpack   (K=384)  grid 313x5 = 1565 blocks
    k_mgemm<64, 128, 1, 4, 0><<<dim3(mb64, NXY / 128), 256, 0, stream>>>(
        A1, WpH, WpL, C1, nullptr, Nn, NXY, KXY,
        nullptr, nullptr, nullptr);

    // fused gather + msg GEMM + memory update -> updh   (5000 blocks, 4 nodes each)
    k_gmsg<<<(Nn + 3) / 4, 256, 0, stream>>>(C1, sorted_w, sorted_tgt, startb, counts,
                                             W1, b1, W2H, W2L, b2, A1, decay, updh, Nn);

    // G3a: e f16 = leaky(updated @ We^T + be)   (M=20000, N=64, K=256)  313 blocks
    k_mgemm<64, 64, 2, 2, 2><<<dim3(mb64, 1), 256, 0, stream>>>(
        updh, WeH, WeL, ebuf, nullptr, Nn, MDIM, LM,
        be, nullptr, nullptr);

    // G3b: out = theta*static + (1-theta)*leaky(e @ Ws^T + bs)  (M=20000,N=128,K=64) 313 blocks
    k_mgemm<64, 128, 1, 4, 3><<<dim3(mb64, 1), 256, 0, stream>>>(
        ebuf, WsH, WsL, nullptr, out, Nn, EDIM, MDIM,
        bs, static_emb, theta);
}

// Round 13
// 262.772 us; speedup vs baseline: 1.1266x; 1.1266x over previous
//
#include <hip/hip_runtime.h>

// ---------------- problem constants ----------------
constexpr int LDIM = 4;
constexpr int MDIM = 64;
constexpr int FDIM = 128;
constexpr int EDIM = 128;
constexpr int RAWD = 641;
constexpr int HDIM = 320;
constexpr int LM   = LDIM * MDIM;   // 256
constexpr int KXY  = LM + FDIM;     // 384
constexpr int NXY  = 2 * HDIM;      // 640

typedef _Float16 f16x8 __attribute__((ext_vector_type(8)));
typedef _Float16 f16x4 __attribute__((ext_vector_type(4)));
typedef float    f32x4 __attribute__((ext_vector_type(4)));

constexpr float WSCALE  = 256.f;       // weights pre-scaled so lo-plane is f16-normal
constexpr float WSINV   = 1.f / 256.f; // exact pow2, applied in epilogue

// ---------------- small event/node kernels ----------------
__global__ void k_init(int* t_node_bits, int* counts, int* cursor2, int* cursor, int Nn)
{
    int n = blockIdx.x * blockDim.x + threadIdx.x;
    if (n < Nn) {
        t_node_bits[n] = 0xBF800000;  // -1.0f; timestamps >= 0
        counts[n]  = 0;
        cursor2[n] = 0;
    }
    if (n == 0) cursor[0] = 0;
}

__global__ void k_ev1(const int* __restrict__ src, const float* __restrict__ ts,
                      int* t_node_bits, int* counts, int Bev)
{
    int b = blockIdx.x * blockDim.x + threadIdx.x;
    if (b >= Bev) return;
    int s = src[b];
    atomicMax(&t_node_bits[s], __float_as_int(ts[b]));
    atomicAdd(&counts[s], 1);
}

__global__ void k_node(const int* __restrict__ t_node_bits, const int* __restrict__ counts,
                       const float* __restrict__ last_update, const float* __restrict__ lambs,
                       float* t_safe, float* decay, int* start, int* cursor, int Nn)
{
    int n = blockIdx.x * blockDim.x + threadIdx.x;
    if (n >= Nn) return;
    int c = counts[n];
    float lu = last_update[n];
    float tsn = (c > 0) ? __int_as_float(t_node_bits[n]) : lu;
    t_safe[n] = tsn;
    float d = tsn - lu;
    #pragma unroll
    for (int li = 0; li < LDIM; ++li)
        decay[n * LDIM + li] = expf(-d * lambs[li]);
    start[n] = atomicAdd(cursor, c);
}

__global__ void k_ev2(const int* __restrict__ src, const int* __restrict__ tgt,
                      const float* __restrict__ ts, const float* __restrict__ t_safe,
                      const int* __restrict__ start, int* cursor2,
                      const float* __restrict__ lambs,
                      int* sorted_tgt, float4* sorted_w, int Bev)
{
    int b = blockIdx.x * blockDim.x + threadIdx.x;
    if (b >= Bev) return;
    int s = src[b];
    int pos = start[s] + atomicAdd(&cursor2[s], 1);
    sorted_tgt[pos] = tgt[b];
    float dt = t_safe[s] - ts[b];
    sorted_w[pos] = make_float4(expf(-dt * lambs[0]), expf(-dt * lambs[1]),
                                expf(-dt * lambs[2]), expf(-dt * lambs[3]));
}

// ---------------- prep: weights [N][K] scaled f16 hi/lo + vectorized A1 pack ----------------
__global__ void k_prep(const float* __restrict__ W1, const float* __restrict__ W2,
                       const float* __restrict__ We, const float* __restrict__ Ws,
                       const float* __restrict__ mem, const float* __restrict__ nf,
                       _Float16* WpH, _Float16* WpL, _Float16* W2H, _Float16* W2L,
                       _Float16* WeH, _Float16* WeL, _Float16* WsH, _Float16* WsL,
                       _Float16* A1, int packq)
{
    int idx = blockIdx.x * blockDim.x + threadIdx.x;
    constexpr int T1 = NXY * KXY;    // 245760  Wpack [640][384]
    constexpr int T2 = MDIM * HDIM;  // 20480   W2 [64][320]
    constexpr int T3 = MDIM * LM;    // 16384   We [64][256]
    constexpr int T4 = EDIM * MDIM;  // 8192    Ws [128][64]
    constexpr int TW = T1 + T2 + T3 + T4;
    if (idx < TW) {
        float v; _Float16 *H, *L; int o;
        if (idx < T1) {
            int n = idx / KXY, k = idx % KXY;
            if (n < HDIM) {
                v = (k < LM) ? W1[(long)n * RAWD + k] : 0.f;            // X cols: src-mem
            } else {
                int hh = n - HDIM;
                v = (k < LM) ? W1[(long)hh * RAWD + LM + k]              // Y cols: tgt-mem
                             : W1[(long)hh * RAWD + 2 * LM + (k - LM)];  //         tgt-feat
            }
            H = WpH; L = WpL; o = idx;
        } else if (idx < T1 + T2) {
            o = idx - T1; v = W2[o]; H = W2H; L = W2L;
        } else if (idx < T1 + T2 + T3) {
            o = idx - T1 - T2; v = We[o]; H = WeH; L = WeL;
        } else {
            o = idx - T1 - T2 - T3; v = Ws[o]; H = WsH; L = WsL;
        }
        float xs = WSCALE * v;
        _Float16 hh = (_Float16)xs;
        _Float16 ll = (_Float16)(xs - (float)hh);
        H[o] = hh; L[o] = ll;
    } else {
        int r = idx - TW;                        // float4-quad id
        if (r < packq) {
            constexpr int KQ = KXY / 4;          // 96 quads per row
            int n = r / KQ, kq = r % KQ, k = kq * 4;
            float4 v = (k < LM) ? *(const float4*)(mem + (long)n * LM + k)
                                : *(const float4*)(nf  + (long)n * FDIM + (k - LM));
            f16x4 o4 = {(_Float16)v.x, (_Float16)v.y, (_Float16)v.z, (_Float16)v.w};
            *(f16x4*)(A1 + (long)n * KXY + k) = o4;
        }
    }
}

// ---------------- gather: wave-per-node, 1-deep software pipeline ----------------
// lane owns hidden indices [4*lane .. 4*lane+3] and [256+lane]
__global__ __launch_bounds__(256) void k_gather(
    const _Float16* __restrict__ C1, const float4* __restrict__ sorted_w,
    const int* __restrict__ sorted_tgt, const int* __restrict__ startb,
    const int* __restrict__ counts,
    const float* __restrict__ W1, const float* __restrict__ b1,
    _Float16* __restrict__ h, int Nn)
{
    const int lane = threadIdx.x & 63;
    const int wv   = threadIdx.x >> 6;          // wave id 0..3, one node per wave
    float4 b4 = *(const float4*)&b1[lane * 4];
    float bbA[4] = {b4.x, b4.y, b4.z, b4.w};
    float bbB = b1[256 + lane];
    float wlA[4], wlB;
    #pragma unroll
    for (int j = 0; j < 4; ++j)
        wlA[j] = W1[(long)(lane * 4 + j) * RAWD + (RAWD - 1)];
    wlB = W1[(long)(256 + lane) * RAWD + (RAWD - 1)];

    for (int n = blockIdx.x * 4 + wv; n < Nn; n += gridDim.x * 4) {
        int cnt = counts[n];
        if (cnt == 0) continue;                  // row poison masked in G2 epilogue
        int st = startb[n];
        float zA[4][4], zB[4], sw[4];
        #pragma unroll
        for (int li = 0; li < 4; ++li) { zB[li] = 0.f; sw[li] = 0.f; }
        #pragma unroll
        for (int j = 0; j < 4; ++j)
            #pragma unroll
            for (int li = 0; li < 4; ++li) zA[j][li] = 0.f;

        // stage 0 preload
        float4 w0 = sorted_w[st];
        int    t0 = sorted_tgt[st];
        const _Float16* yr0 = C1 + (long)t0 * NXY + HDIM;
        f16x4 yA0 = *(const f16x4*)(yr0 + lane * 4);
        float  yB0 = (float)yr0[256 + lane];

        for (int e = 0; e < cnt; ++e) {
            float4 w = w0; f16x4 yA = yA0; float yB = yB0;
            if (e + 1 < cnt) {                   // prefetch next event
                w0 = sorted_w[st + e + 1];
                int t1 = sorted_tgt[st + e + 1];
                const _Float16* yr1 = C1 + (long)t1 * NXY + HDIM;
                yA0 = *(const f16x4*)(yr1 + lane * 4);
                yB0 = (float)yr1[256 + lane];
            }
            float wf[4] = {w.x, w.y, w.z, w.w};
            sw[0] += w.x; sw[1] += w.y; sw[2] += w.z; sw[3] += w.w;
            #pragma unroll
            for (int j = 0; j < 4; ++j) {
                float yv = (float)yA[j];
                #pragma unroll
                for (int li = 0; li < 4; ++li) zA[j][li] += wf[li] * yv;
            }
            #pragma unroll
            for (int li = 0; li < 4; ++li) zB[li] += wf[li] * yB;
        }

        const _Float16* xr = C1 + (long)n * NXY;
        f16x4 xA4 = *(const f16x4*)(xr + lane * 4);
        float xB = (float)xr[256 + lane] + wlB;
        float xA[4];
        #pragma unroll
        for (int j = 0; j < 4; ++j) xA[j] = (float)xA4[j] + wlA[j];
        #pragma unroll
        for (int li = 0; li < 4; ++li) {
            _Float16* hr = h + ((long)n * LDIM + li) * HDIM;
            f16x4 hv;
            #pragma unroll
            for (int j = 0; j < 4; ++j)
                hv[j] = (_Float16)fmaxf(xA[j] * sw[li] + zA[j][li] + bbA[j], 0.f);
            *(f16x4*)(hr + lane * 4) = hv;
            hr[256 + lane] = (_Float16)fmaxf(xB * sw[li] + zB[li] + bbB, 0.f);
        }
    }
}

// ---------------- f16 2-product MFMA GEMM (round-10 template) ----------------
// C[M][N] = A[M][K](f16) @ (Bh+Bl)[K][N], B stored [N][K] scaled by 256.
// LDS [rows][32k] f16 (64B rows), 16B-chunk XOR swizzle: phys_chunk = kc ^ ((row>>1)&3).
// EPI: 0 -> f16 C; 1 -> updated f16 (A1-mem*decay + mask).
template <int BM, int BN, int WM, int WN, int EPI>
__global__ __launch_bounds__(256) void k_mgemm(
    const _Float16* __restrict__ Ag,
    const _Float16* __restrict__ Bgh, const _Float16* __restrict__ Bgl,
    _Float16* __restrict__ Ch,
    int M, int N, int K,
    const float* __restrict__ bias, const _Float16* __restrict__ x1h,
    const float* __restrict__ x2, const int* __restrict__ icnts)
{
    constexpr int BK = 32;
    constexpr int WROWS = BM / WM, WCOLS = BN / WN;
    constexpr int SM = WROWS / 16, SN = WCOLS / 16;
    static_assert(WM * WN == 4 && SM * 16 == WROWS && SN * 16 == WCOLS, "");
    static_assert((BM * 4) % 256 == 0 && (BN * 4) % 256 == 0, "");
    __shared__ _Float16 Ash[BM * BK];
    __shared__ _Float16 Bsh[BN * BK], Bsl[BN * BK];
    const int tid  = threadIdx.x;
    const int w    = tid >> 6, lane = tid & 63;
    const int wm   = w / WN,   wn   = w % WN;
    const int lrow = lane & 15, lq = lane >> 4;
    const long m0 = (long)blockIdx.x * BM;
    const int  n0 = blockIdx.y * BN;

    f32x4 acc[SM][SN];
    #pragma unroll
    for (int s = 0; s < SM; ++s)
        #pragma unroll
        for (int t = 0; t < SN; ++t) acc[s][t] = (f32x4){0.f, 0.f, 0.f, 0.f};

    for (int k0 = 0; k0 < K; k0 += BK) {
        #pragma unroll
        for (int f0 = 0; f0 < BM * 4; f0 += 256) {
            int c = f0 + tid;
            int row = c >> 2, kc = c & 3;
            long gm = m0 + row; if (gm > M - 1) gm = M - 1;
            int soff = row * BK + ((kc ^ ((row >> 1) & 3)) << 3);
            *(int4*)&Ash[soff] = *(const int4*)(Ag + gm * (long)K + k0 + kc * 8);
        }
        #pragma unroll
        for (int f0 = 0; f0 < BN * 4; f0 += 256) {
            int c = f0 + tid;
            int row = c >> 2, kc = c & 3;
            long goff = (long)(n0 + row) * K + k0 + kc * 8;
            int soff = row * BK + ((kc ^ ((row >> 1) & 3)) << 3);
            *(int4*)&Bsh[soff] = *(const int4*)(Bgh + goff);
            *(int4*)&Bsl[soff] = *(const int4*)(Bgl + goff);
        }
        __syncthreads();

        f16x8 a[SM], bh[SN], bl[SN];
        #pragma unroll
        for (int s = 0; s < SM; ++s) {
            int row = wm * WROWS + s * 16 + lrow;
            a[s] = *(const f16x8*)&Ash[row * BK + ((lq ^ ((row >> 1) & 3)) << 3)];
        }
        #pragma unroll
        for (int t = 0; t < SN; ++t) {
            int row = wn * WCOLS + t * 16 + lrow;
            int off = row * BK + ((lq ^ ((row >> 1) & 3)) << 3);
            bh[t] = *(const f16x8*)&Bsh[off];
            bl[t] = *(const f16x8*)&Bsl[off];
        }
        #pragma unroll
        for (int s = 0; s < SM; ++s)
            #pragma unroll
            for (int t = 0; t < SN; ++t) {
                acc[s][t] = __builtin_amdgcn_mfma_f32_16x16x32_f16(a[s], bh[t], acc[s][t], 0, 0, 0);
                acc[s][t] = __builtin_amdgcn_mfma_f32_16x16x32_f16(a[s], bl[t], acc[s][t], 0, 0, 0);
            }
        __syncthreads();
    }

    #pragma unroll
    for (int s = 0; s < SM; ++s) {
        #pragma unroll
        for (int t = 0; t < SN; ++t) {
            #pragma unroll
            for (int r = 0; r < 4; ++r) {
                long grow = m0 + wm * WROWS + s * 16 + lq * 4 + r;
                if (grow >= M) continue;
                int col = n0 + wn * WCOLS + t * 16 + lrow;
                float v = acc[s][t][r] * WSINV;
                long idx = grow * (long)N + col;
                if constexpr (EPI == 0) {
                    Ch[idx] = (_Float16)v;
                } else {
                    // updated = memory(f16 A1)*decay + where(has, msg+b2, 0)
                    float vb = v + bias[col];
                    bool has = icnts[grow >> 2] > 0;
                    float mv = (float)x1h[(grow >> 2) * KXY + (grow & 3) * MDIM + col];
                    float u = mv * x2[grow] + (has ? vb : 0.f);
                    Ch[idx] = (_Float16)u;
                }
            }
        }
    }
}

// ---------------- fused tail: e = leaky(upd@We^T+be); out = th*se + (1-th)*leaky(e@Ws^T+bs)
// Block = 64 rows, 4 waves. GEMM1 (2x2 waves, K=256) -> e[64][64] in LDS ->
// GEMM2 (1x4 waves, K=64, N=128). Fixed trip counts -> uniform barriers (no tail coupling).
__global__ __launch_bounds__(256) void k_tail(
    const _Float16* __restrict__ upd,
    const _Float16* __restrict__ WeH, const _Float16* __restrict__ WeL,
    const _Float16* __restrict__ WsH, const _Float16* __restrict__ WsL,
    const float* __restrict__ be, const float* __restrict__ bs,
    const float* __restrict__ static_emb, const float* __restrict__ theta,
    float* __restrict__ out, int M)
{
    constexpr int BK = 32, EP = 72;              // e_s row stride (f16): 144B -> 2-way banks
    __shared__ _Float16 Ash[64 * BK];
    __shared__ _Float16 Bsh[64 * BK], Bsl[64 * BK];
    __shared__ _Float16 es[64][EP];
    const int tid  = threadIdx.x;
    const int w    = tid >> 6, lane = tid & 63;
    const int lrow = lane & 15, lq = lane >> 4;
    const long m0 = (long)blockIdx.x * 64;

    // ---- GEMM1: 64x64, K=256, waves 2x2 (SM=SN=2) ----
    {
        const int wm = w >> 1, wn = w & 1;
        f32x4 acc[2][2];
        #pragma unroll
        for (int s = 0; s < 2; ++s)
            #pragma unroll
            for (int t = 0; t < 2; ++t) acc[s][t] = (f32x4){0.f, 0.f, 0.f, 0.f};

        for (int k0 = 0; k0 < LM; k0 += BK) {
            {
                int c = tid;                     // 64 rows x 4 chunks = 256
                int row = c >> 2, kc = c & 3;
                long gm = m0 + row; if (gm > M - 1) gm = M - 1;
                int soff = row * BK + ((kc ^ ((row >> 1) & 3)) << 3);
                *(int4*)&Ash[soff] = *(const int4*)(upd + gm * (long)LM + k0 + kc * 8);
                long goff = (long)row * LM + k0 + kc * 8;   // B rows = 64 msg cols
                *(int4*)&Bsh[soff] = *(const int4*)(WeH + goff);
                *(int4*)&Bsl[soff] = *(const int4*)(WeL + goff);
            }
            __syncthreads();
            f16x8 a[2], bh[2], bl[2];
            #pragma unroll
            for (int s = 0; s < 2; ++s) {
                int row = wm * 32 + s * 16 + lrow;
                a[s] = *(const f16x8*)&Ash[row * BK + ((lq ^ ((row >> 1) & 3)) << 3)];
            }
            #pragma unroll
            for (int t = 0; t < 2; ++t) {
                int row = wn * 32 + t * 16 + lrow;
                int off = row * BK + ((lq ^ ((row >> 1) & 3)) << 3);
                bh[t] = *(const f16x8*)&Bsh[off];
                bl[t] = *(const f16x8*)&Bsl[off];
            }
            #pragma unroll
            for (int s = 0; s < 2; ++s)
                #pragma unroll
                for (int t = 0; t < 2; ++t) {
                    acc[s][t] = __builtin_amdgcn_mfma_f32_16x16x32_f16(a[s], bh[t], acc[s][t], 0, 0, 0);
                    acc[s][t] = __builtin_amdgcn_mfma_f32_16x16x32_f16(a[s], bl[t], acc[s][t], 0, 0, 0);
                }
            __syncthreads();
        }
        // e = leaky(acc*WSINV + be) -> LDS
        #pragma unroll
        for (int s = 0; s < 2; ++s)
            #pragma unroll
            for (int t = 0; t < 2; ++t) {
                int col = wn * 32 + t * 16 + lrow;
                float bb = be[col];
                #pragma unroll
                for (int r = 0; r < 4; ++r) {
                    int row = wm * 32 + s * 16 + lq * 4 + r;
                    float u = acc[s][t][r] * WSINV + bb;
                    u = u > 0.f ? u : 0.01f * u;
                    es[row][col] = (_Float16)u;
                }
            }
    }
    __syncthreads();

    // ---- GEMM2: 64x128, K=64, waves 1x4 (SM=4, SN=2); wave w covers cols 32w..32w+31 ----
    {
        f32x4 acc[4][2];
        #pragma unroll
        for (int s = 0; s < 4; ++s)
            #pragma unroll
            for (int t = 0; t < 2; ++t) acc[s][t] = (f32x4){0.f, 0.f, 0.f, 0.f};

        #pragma unroll
        for (int k0 = 0; k0 < MDIM; k0 += BK) {
            f16x8 a[4], bh[2], bl[2];
            #pragma unroll
            for (int s = 0; s < 4; ++s)
                a[s] = *(const f16x8*)&es[s * 16 + lrow][k0 + lq * 8];
            #pragma unroll
            for (int t = 0; t < 2; ++t) {
                int col = w * 32 + t * 16 + lrow;
                long bo = (long)col * MDIM + k0 + lq * 8;
                bh[t] = *(const f16x8*)&WsH[bo];
                bl[t] = *(const f16x8*)&WsL[bo];
            }
            #pragma unroll
            for (int s = 0; s < 4; ++s)
                #pragma unroll
                for (int t = 0; t < 2; ++t) {
                    acc[s][t] = __builtin_amdgcn_mfma_f32_16x16x32_f16(a[s], bh[t], acc[s][t], 0, 0, 0);
                    acc[s][t] = __builtin_amdgcn_mfma_f32_16x16x32_f16(a[s], bl[t], acc[s][t], 0, 0, 0);
                }
        }

        float th = theta[0];
        #pragma unroll
        for (int s = 0; s < 4; ++s)
            #pragma unroll
            for (int t = 0; t < 2; ++t) {
                int col = w * 32 + t * 16 + lrow;
                float bb = bs[col];
                #pragma unroll
                for (int r = 0; r < 4; ++r) {
                    long grow = m0 + s * 16 + lq * 4 + r;
                    if (grow >= M) continue;
                    float u = acc[s][t][r] * WSINV + bb;
                    u = u > 0.f ? u : 0.01f * u;
                    long idx = grow * (long)EDIM + col;
                    out[idx] = th * static_emb[idx] + (1.f - th) * u;
                }
            }
    }
}

// ---------------- launcher ----------------
extern "C" void kernel_launch(void* const* d_in, const int* in_sizes, int n_in,
                              void* d_out, int out_size, void* d_ws, size_t ws_size,
                              hipStream_t stream)
{
    (void)n_in; (void)out_size; (void)ws_size;
    const float* node_features = (const float*)d_in[0];
    const float* memory        = (const float*)d_in[1];
    const float* last_update   = (const float*)d_in[2];
    const float* lambs         = (const float*)d_in[3];
    const float* theta         = (const float*)d_in[4];
    const float* static_emb    = (const float*)d_in[5];
    const float* W1            = (const float*)d_in[6];
    const float* b1            = (const float*)d_in[7];
    const float* W2            = (const float*)d_in[8];
    const float* b2            = (const float*)d_in[9];
    const float* We            = (const float*)d_in[10];
    const float* be            = (const float*)d_in[11];
    const float* Ws            = (const float*)d_in[12];
    const float* bs            = (const float*)d_in[13];
    const float* timestamps    = (const float*)d_in[14];
    const int*   src           = (const int*)d_in[15];
    const int*   tgt           = (const int*)d_in[16];
    float* out = (float*)d_out;

    const int Nn  = in_sizes[2];   // 20000
    const int Bev = in_sizes[14];  // 100000

    char* base = (char*)d_ws;
    size_t off = 0;
    auto take = [&](size_t bytes) -> void* {
        off = (off + 255) & ~(size_t)255;
        void* r = base + off;
        off += bytes;
        return r;
    };
    int*    t_node_bits = (int*)   take((size_t)Nn * 4);
    int*    counts      = (int*)   take((size_t)Nn * 4);
    int*    startb      = (int*)   take((size_t)Nn * 4);
    int*    cursor2     = (int*)   take((size_t)Nn * 4);
    int*    cursor      = (int*)   take(256);
    float*  t_safe      = (float*) take((size_t)Nn * 4);
    float*  decay       = (float*) take((size_t)Nn * LDIM * 4);
    int*    sorted_tgt  = (int*)   take((size_t)Bev * 4);
    float4* sorted_w    = (float4*)take((size_t)Bev * 16);
    _Float16* WpH = (_Float16*)take((size_t)NXY * KXY * 2);
    _Float16* WpL = (_Float16*)take((size_t)NXY * KXY * 2);
    _Float16* W2H = (_Float16*)take((size_t)MDIM * HDIM * 2);
    _Float16* W2L = (_Float16*)take((size_t)MDIM * HDIM * 2);
    _Float16* WeH = (_Float16*)take((size_t)MDIM * LM * 2);
    _Float16* WeL = (_Float16*)take((size_t)MDIM * LM * 2);
    _Float16* WsH = (_Float16*)take((size_t)EDIM * MDIM * 2);
    _Float16* WsL = (_Float16*)take((size_t)EDIM * MDIM * 2);
    _Float16* A1  = (_Float16*)take((size_t)Nn * KXY * 2);            // 15.4 MB
    _Float16* C1  = (_Float16*)take((size_t)Nn * NXY * 2);            // 25.6 MB
    _Float16* hbuf= (_Float16*)take((size_t)Nn * LDIM * HDIM * 2);    // 51.2 MB
    _Float16* updh= (_Float16*)take((size_t)Nn * LM * 2);             // 10.2 MB

    const int tb = 256;
    k_init<<<(Nn + tb - 1) / tb, tb, 0, stream>>>(t_node_bits, counts, cursor2, cursor, Nn);
    k_ev1<<<(Bev + tb - 1) / tb, tb, 0, stream>>>(src, timestamps, t_node_bits, counts, Bev);
    k_node<<<(Nn + tb - 1) / tb, tb, 0, stream>>>(t_node_bits, counts, last_update, lambs,
                                                  t_safe, decay, startb, cursor, Nn);
    k_ev2<<<(Bev + tb - 1) / tb, tb, 0, stream>>>(src, tgt, timestamps, t_safe,
                                                  startb, cursor2, lambs,
                                                  sorted_tgt, sorted_w, Bev);
    const int packq = Nn * KXY / 4;
    const int preptot = NXY * KXY + MDIM * HDIM + MDIM * LM + EDIM * MDIM + packq;
    k_prep<<<(preptot + tb - 1) / tb, tb, 0, stream>>>(W1, W2, We, Ws,
                                                       memory, node_features,
                                                       WpH, WpL, W2H, W2L,
                                                       WeH, WeL, WsH, WsL,
                                                       A1, packq);

    const int mb64 = (Nn + 63) / 64;    // 313

    // G1: C1[20000][640](f16) = A1 @ Wpack   (K=384)  grid 313x5 = 1565 blocks
    k_mgemm<64, 128, 1, 4, 0><<<dim3(mb64, NXY / 128), 256, 0, stream>>>(
        A1, WpH, WpL, C1, Nn, NXY, KXY,
        nullptr, nullptr, nullptr, nullptr);

    // gather: h f16 [80000][320], software-pipelined event loop
    k_gather<<<5000, 256, 0, stream>>>(C1, sorted_w, sorted_tgt, startb, counts,
                                       W1, b1, hbuf, Nn);

    // G2: updated f16 = (h @ W2^T + b2) masked + mem*decay  (M=80000,N=64,K=320) 1250 blocks
    k_mgemm<64, 64, 2, 2, 1><<<dim3(Nn * LDIM / 64, 1), 256, 0, stream>>>(
        hbuf, W2H, W2L, updh, Nn * LDIM, MDIM, HDIM,
        b2, A1, decay, counts);

    // fused tail: e + out in one kernel (313 blocks)
    k_tail<<<mb64, 256, 0, stream>>>(updh, WeH, WeL, WsH, WsL,
                                     be, bs, static_emb, theta, out, Nn);
}